// Round 9
// baseline (174.107 us; speedup 1.0000x reference)
//
#include <hip/hip_runtime.h>
#include <hip/hip_fp16.h>

#define D 64
#define BETA 0.9f
#define ALPHA 0.1f
#define CB_SHIFT 10
#define CB_ROWS 1024          // rows per coarse bucket
#define CAP_SHIFT 14
#define CAP (1 << CAP_SHIFT)  // edge slots per bucket (16384 >> ~10.2K mean)
#define SA_BLOCKS 128         // prep: stage-A binning blocks
#define CC_BLOCKS 256         // prep: concat/convert blocks
// tmp packing: col in bits 0..17 (N < 262144), row_local in bits 18..27

typedef __attribute__((ext_vector_type(16))) int int16v;

// ---- prep: stageA binning (blocks 0..127) + concat-fp16 + flag2 zero ----
__global__ void prep(const int* __restrict__ rows, const int* __restrict__ cols,
                     const float* __restrict__ vals, int E,
                     int* __restrict__ gcur, int2* __restrict__ tmp,
                     const float* __restrict__ u, const float* __restrict__ it,
                     long long UD, long long ND, __half* __restrict__ x,
                     int* __restrict__ flag2, int N) {
    __shared__ int hist[256];
    __shared__ int cur[256];
    int t = threadIdx.x;  // blockDim = 1024
    if (blockIdx.x < SA_BLOCKS) {
        // ---- stage A: bin edges into slack buckets (single-writer chunks) ----
        if (t < 256) hist[t] = 0;
        __syncthreads();
        int chunk = (E + SA_BLOCKS - 1) / SA_BLOCKS;
        int beg = blockIdx.x * chunk;
        int end = min(beg + chunk, E);
        for (int e = beg + t; e < end; e += 1024)
            atomicAdd(&hist[rows[e] >> CB_SHIFT], 1);
        __syncthreads();
        if (t < 256) {
            int h = hist[t];
            cur[t] = h ? atomicAdd(&gcur[t], h) : 0;
        }
        __syncthreads();
        for (int e = beg + t; e < end; e += 1024) {
            int r = rows[e];
            int cb = r >> CB_SHIFT;
            int p = atomicAdd(&cur[cb], 1);
            tmp[((size_t)cb << CAP_SHIFT) + p] =
                make_int2(cols[e] | ((r & (CB_ROWS - 1)) << 18), __float_as_int(vals[e]));
        }
    } else {
        // ---- concat + fp32->fp16 convert; also zero flag2 ----
        int lb = blockIdx.x - SA_BLOCKS;
        long long n4 = ND >> 2;
        long long stride = (long long)CC_BLOCKS * 1024;
        for (long long i4 = (long long)lb * 1024 + t; i4 < n4; i4 += stride) {
            long long base = i4 << 2;
            float4 v = (base < UD) ? ((const float4*)u)[i4]
                                   : ((const float4*)it)[(base - UD) >> 2];
            __half2* dst = (__half2*)(x + base);
            dst[0] = __floats2half2_rn(v.x, v.y);
            dst[1] = __floats2half2_rn(v.z, v.w);
        }
        for (long long i = (long long)lb * 1024 + t; i < N; i += stride)
            flag2[i] = 0;
    }
}

// ---- Stage B: per-bucket local count + scan + scatter; emits meta --------
__global__ void stageB(const int* __restrict__ bcnt, int N,
                       const int2* __restrict__ tmp,
                       int2* __restrict__ epack, int2* __restrict__ meta) {
    __shared__ int sc[CB_ROWS];
    __shared__ int cur[CB_ROWS];
    int cb = blockIdx.x;
    int t = threadIdx.x;  // blockDim = CB_ROWS
    size_t base = (size_t)cb << CAP_SHIFT;
    int nb = bcnt[cb];
    sc[t] = 0;
    __syncthreads();
    for (int e = t; e < nb; e += CB_ROWS)
        atomicAdd(&sc[((unsigned)tmp[base + e].x) >> 18], 1);
    __syncthreads();
    int mycnt = sc[t];
    for (int off = 1; off < CB_ROWS; off <<= 1) {
        int v = (t >= off) ? sc[t - off] : 0;
        __syncthreads();
        sc[t] += v;
        __syncthreads();
    }
    int excl = sc[t] - mycnt;     // exclusive prefix within bucket
    cur[t] = excl;
    int r = (cb << CB_SHIFT) + t;
    if (r < N) meta[r] = make_int2((int)base + excl, mycnt);
    __syncthreads();
    for (int e = t; e < nb; e += CB_ROWS) {
        int2 pk = tmp[base + e];
        int rl = ((unsigned)pk.x) >> 18;
        int p = atomicAdd(&cur[rl], 1);
        epack[base + p] = make_int2(pk.x & ((1 << 18) - 1), pk.y);
    }
}

// ---- SpMM core: scalar edge fetch, 16 edges per SMEM stall ---------------
// Two back-to-back s_load_dwordx16 + ONE lgkmcnt(0) wait (SMEM returns may be
// out-of-order, so partial lgkm waits are illegal — but batching two loads
// halves the stall count). Tail: col select + masked addend (NaN-proof).
__device__ __forceinline__ float row_dot_s(const int2* __restrict__ ep,
                                           int beg, int cnt,
                                           const __half* __restrict__ x, int lane) {
    float acc = 0.f;
    int e = 0;
    int full = cnt & ~15;
    for (; e < full; e += 16) {
        int16v ed0, ed1;
        asm volatile("s_load_dwordx16 %0, %2, 0x0\n\t"
                     "s_load_dwordx16 %1, %2, 0x40\n\t"
                     "s_waitcnt lgkmcnt(0)"
                     : "=s"(ed0), "=s"(ed1)
                     : "s"(ep + beg + e));
#define EDGEF(S, k)                                                           \
        acc += __int_as_float(S[2 * (k) + 1]) *                               \
               __half2float(x[((size_t)(unsigned)S[2 * (k)] << 6) + lane]);
        EDGEF(ed0, 0) EDGEF(ed0, 1) EDGEF(ed0, 2) EDGEF(ed0, 3)
        EDGEF(ed0, 4) EDGEF(ed0, 5) EDGEF(ed0, 6) EDGEF(ed0, 7)
        EDGEF(ed1, 0) EDGEF(ed1, 1) EDGEF(ed1, 2) EDGEF(ed1, 3)
        EDGEF(ed1, 4) EDGEF(ed1, 5) EDGEF(ed1, 6) EDGEF(ed1, 7)
#undef EDGEF
    }
    int rem = cnt - e;  // 0..15
    if (rem > 0) {
        int16v ed0, ed1;
        asm volatile("s_load_dwordx16 %0, %2, 0x0\n\t"
                     "s_load_dwordx16 %1, %2, 0x40\n\t"
                     "s_waitcnt lgkmcnt(0)"
                     : "=s"(ed0), "=s"(ed1)
                     : "s"(ep + beg + e));
#define EDGET(S, k, b)                                                        \
        {                                                                     \
            bool ok = ((b) + (k)) < rem;                                      \
            int col = ok ? S[2 * (k)] : 0;                                    \
            float v = ok ? __int_as_float(S[2 * (k) + 1]) : 0.0f;             \
            float xv = __half2float(x[((size_t)(unsigned)col << 6) + lane]);  \
            acc += ok ? v * xv : 0.0f;                                        \
        }
        EDGET(ed0, 0, 0) EDGET(ed0, 1, 0) EDGET(ed0, 2, 0) EDGET(ed0, 3, 0)
        EDGET(ed0, 4, 0) EDGET(ed0, 5, 0) EDGET(ed0, 6, 0) EDGET(ed0, 7, 0)
        EDGET(ed1, 0, 8) EDGET(ed1, 1, 8) EDGET(ed1, 2, 8) EDGET(ed1, 3, 8)
        EDGET(ed1, 4, 8) EDGET(ed1, 5, 8) EDGET(ed1, 6, 8) EDGET(ed1, 7, 8)
#undef EDGET
    }
    return acc;
}

// Layer 0: x0 = A @ xcat (blocks < spmm_blocks); tail blocks mark flag2.
// Block 0 also zeroes ego1 row 0 (tmp-alias garbage guard for dead tail
// gathers in spmm_l1/out_slots).
__global__ void spmm_l0(const int2* __restrict__ meta, const int2* __restrict__ epack,
                        const __half* __restrict__ xcat, int N, __half* __restrict__ y,
                        __half* __restrict__ ego1_row0,
                        const int* __restrict__ users, const int* __restrict__ items,
                        int B, int U, int* __restrict__ flag2, int spmm_blocks) {
    int lane = threadIdx.x & 63;
    int wv = threadIdx.x >> 6;
    if (blockIdx.x >= spmm_blocks) {
        // mark flag2[c]=1 for every column c in the 2B output rows' edge lists
        int w = (blockIdx.x - spmm_blocks) * 4 + wv;
        if (w >= 2 * B) return;
        int r = (w < B) ? users[w] : U + items[w - B];
        int2 m = meta[r];
        for (int e = m.x + lane; e < m.x + m.y; e += 64)
            flag2[epack[e].x] = 1;
        return;
    }
    if (blockIdx.x == 0 && threadIdx.x < D)
        ego1_row0[threadIdx.x] = __float2half(0.0f);
    int r = blockIdx.x * 4 + wv;
    if (r >= N) return;
    r = __builtin_amdgcn_readfirstlane(r);
    int2 m = meta[r];
    int beg = __builtin_amdgcn_readfirstlane(m.x);
    int cnt = __builtin_amdgcn_readfirstlane(m.y);
    float acc = row_dot_s(epack, beg, cnt, xcat, lane);
    y[((size_t)r << 6) + lane] = __float2half(acc);
}

// Layer 1 at flagged rows: ego1 = BETA*(A@x0) + ALPHA*x0
__global__ void spmm_l1(const int2* __restrict__ meta, const int2* __restrict__ epack,
                        const __half* __restrict__ x0, const int* __restrict__ flag2,
                        int N, __half* __restrict__ y) {
    int lane = threadIdx.x & 63;
    int r = blockIdx.x * (blockDim.x >> 6) + (threadIdx.x >> 6);
    if (r >= N) return;
    r = __builtin_amdgcn_readfirstlane(r);
    if (flag2[r] == 0) return;
    int2 m = meta[r];
    int beg = __builtin_amdgcn_readfirstlane(m.x);
    int cnt = __builtin_amdgcn_readfirstlane(m.y);
    float acc = row_dot_s(epack, beg, cnt, x0, lane);
    float x0v = __half2float(x0[((size_t)r << 6) + lane]);
    y[((size_t)r << 6) + lane] = __float2half(BETA * acc + ALPHA * x0v);
}

// Layer 2 only at the 2B output slots, fp32 out
__global__ void out_slots(const int* __restrict__ users, const int* __restrict__ items,
                          int B, int U,
                          const int2* __restrict__ meta, const int2* __restrict__ epack,
                          const __half* __restrict__ ego1, const __half* __restrict__ x0,
                          float inv_gamma, float* __restrict__ out) {
    int lane = threadIdx.x & 63;
    int w = blockIdx.x * (blockDim.x >> 6) + (threadIdx.x >> 6);
    if (w >= 2 * B) return;
    int r = (w < B) ? users[w] : U + items[w - B];
    r = __builtin_amdgcn_readfirstlane(r);
    int2 m = meta[r];
    int beg = __builtin_amdgcn_readfirstlane(m.x);
    int cnt = __builtin_amdgcn_readfirstlane(m.y);
    float acc = row_dot_s(epack, beg, cnt, ego1, lane);
    float x0v = __half2float(x0[((size_t)r << 6) + lane]);
    out[((size_t)w << 6) + lane] = (BETA * acc + ALPHA * x0v) * inv_gamma;
}

extern "C" void kernel_launch(void* const* d_in, const int* in_sizes, int n_in,
                              void* d_out, int out_size, void* d_ws, size_t ws_size,
                              hipStream_t stream) {
    const int*   users = (const int*)d_in[0];
    const int*   items = (const int*)d_in[1];
    const float* uemb  = (const float*)d_in[2];
    const float* iemb  = (const float*)d_in[3];
    const int*   arows = (const int*)d_in[4];
    const int*   acols = (const int*)d_in[5];
    const float* avals = (const float*)d_in[6];

    const int B = in_sizes[0];
    const int U = in_sizes[2] / D;
    const int I = in_sizes[3] / D;
    const int N = U + I;
    const int E = in_sizes[4];

    const double gamma_d = (double)BETA * BETA * BETA +
                           (double)ALPHA * (1.0 + (double)BETA + (double)BETA * BETA);
    const float inv_gamma = (float)(1.0 / gamma_d);

    const int NCB = (N + CB_ROWS - 1) / CB_ROWS;   // 196 (must be <= 256)

    // Workspace (~105 MB). tmp (slack-bucket staging, 25.7MB) aliases
    // ego1 (25.6MB) + head of x0: tmp dead after stageB; spmm_l0 rewrites all
    // of x0 afterward; ego1 is written at flagged rows (the only rows
    // out_slots gathers) and row 0 is zeroed in spmm_l0 (tail-gather guard).
    char* ws = (char*)d_ws;
    auto align256 = [](size_t x) { return (x + 255) & ~(size_t)255; };
    const size_t ndh_bytes = (size_t)N * D * sizeof(__half);
    const size_t cap_bytes = ((size_t)NCB << CAP_SHIFT) * sizeof(int2) + 128; // + s_load pad
    __half* ego1   = (__half*)ws; ws += align256(ndh_bytes);
    int2*   tmp    = (int2*)ego1;
    __half* x0     = (__half*)ws; ws += align256(ndh_bytes);
    __half* xcat   = (__half*)ws; ws += align256(ndh_bytes);
    int2*  epack   = (int2*)ws;  ws += align256(cap_bytes);
    int2*  meta    = (int2*)ws;  ws += align256((size_t)N * sizeof(int2));
    int*   flag2   = (int*)ws;   ws += align256((size_t)N * sizeof(int));
    int*   gcur    = (int*)ws;   ws += align256(256 * sizeof(int));

    const int threads = 256;
    const int rows_per_block = threads / 64;
    const int spmm_grid = (N + rows_per_block - 1) / rows_per_block;
    const int slot_grid = (2 * B + rows_per_block - 1) / rows_per_block;

    // ---- build: prep (binning ∥ concat ∥ flag2 zero) -> stageB ----
    hipMemsetAsync(gcur, 0, 256 * sizeof(int), stream);
    prep<<<SA_BLOCKS + CC_BLOCKS, 1024, 0, stream>>>(arows, acols, avals, E, gcur, tmp,
                                                     uemb, iemb, (long long)U * D,
                                                     (long long)N * D, xcat, flag2, N);
    stageB<<<NCB, CB_ROWS, 0, stream>>>(gcur, N, tmp, epack, meta);

    // ---- propagation (l0 + flag-marking fused in one dispatch) ----
    spmm_l0<<<spmm_grid + slot_grid, threads, 0, stream>>>(meta, epack, xcat, N, x0, ego1,
                                                           users, items, B, U, flag2,
                                                           spmm_grid);
    spmm_l1<<<spmm_grid, threads, 0, stream>>>(meta, epack, x0, flag2, N, ego1);
    out_slots<<<slot_grid, threads, 0, stream>>>(users, items, B, U, meta, epack,
                                                 ego1, x0, inv_gamma, (float*)d_out);
}